// Round 2
// baseline (569.141 us; speedup 1.0000x reference)
//
#include <hip/hip_runtime.h>
#include <hip/hip_bf16.h>
#include <math.h>

// Problem constants (fixed by the reference's setup_inputs):
//   x: (4, 64, 128, 128)  y: (8, 64, 128, 128)
//   G=4 groups, cg=dc=16, K=3 (K2=9), dilation per group = 2g+1
//   out: (8, 64, 9, 128, 128) fp32
constexpr int HH   = 128;
constexpr int WW   = 128;
constexpr int HWsz = HH * WW;          // 16384

// ---- workspace layout (in floats) ----  (~55 MB total)
constexpr long OFFS_OFF = 0;                             // offsets [4][4][18][HW]
constexpr long MASK_OFF = OFFS_OFF + 4L * 4 * 18 * HWsz; // mask   [4][9][HW]
constexpr long WEO_OFF  = MASK_OFF + 4L * 9 * HWsz;      // Weff_off  [4][16][9][18]
constexpr long WRO_OFF  = WEO_OFF + 4L * 16 * 9 * 18;    // Wraw_off  [4][48][18]
constexpr long WEM_OFF  = WRO_OFF + 4L * 48 * 18;        // Weff_mask [16][9][9]
constexpr long WRM_OFF  = WEM_OFF + 16L * 9 * 9;         // Wraw_mask [48][9]
constexpr long YT_OFF   = WRM_OFF + 48L * 9;             // yT [8*4][HW][16] ch-last
// YT_OFF = 5,323,968 floats -> 16B aligned

// -------------------------------------------------------------------------
// Kernel 0: collapse (3x3 conv 16->16) ∘ (1x1 over first-16 channels) into a
// single effective 3x3 conv 16->O, and transpose the raw-channel 1x1 weights.
// -------------------------------------------------------------------------
__global__ __launch_bounds__(256) void prep_kernel(
    const float* __restrict__ off_pw,   // (4,16,16,3,3)
    const float* __restrict__ off_w,    // (4,18,64)
    const float* __restrict__ mask_pw,  // (16,16,3,3)
    const float* __restrict__ mask_w,   // (9,64)
    float* __restrict__ Weff_off, float* __restrict__ Wraw_off,
    float* __restrict__ Weff_mask, float* __restrict__ Wraw_mask)
{
    const int i = blockIdx.x * 256 + threadIdx.x;
    if (i < 10368) {                       // Weff_off[g][ci][t][o]
        const int o = i % 18; int r = i / 18;
        const int t = r % 9;  r /= 9;
        const int ci = r % 16; const int g = r / 16;
        float s = 0.f;
        for (int co = 0; co < 16; ++co)
            s += off_w[(g * 18 + o) * 64 + co] *
                 off_pw[((g * 16 + co) * 16 + ci) * 9 + t];
        Weff_off[i] = s;
    } else if (i < 10368 + 3456) {         // Wraw_off[g][c][o]
        const int j = i - 10368;
        const int o = j % 18; int r = j / 18;
        const int c = r % 48; const int g = r / 48;
        Wraw_off[j] = off_w[(g * 18 + o) * 64 + 16 + c];
    } else if (i < 10368 + 3456 + 1296) {  // Weff_mask[ci][t][o]
        const int j = i - 13824;
        const int o = j % 9; int r = j / 9;
        const int t = r % 9; const int ci = r / 9;
        float s = 0.f;
        for (int co = 0; co < 16; ++co)
            s += mask_w[o * 64 + co] * mask_pw[((co * 16) + ci) * 9 + t];
        Weff_mask[j] = s;
    } else if (i < 10368 + 3456 + 1296 + 432) { // Wraw_mask[c][o]
        const int j = i - 15120;
        const int o = j % 9; const int c = j / 9;
        Wraw_mask[j] = mask_w[o * 64 + 16 + c];
    }
}

// -------------------------------------------------------------------------
// Kernel 0b: transpose y (B,C,H,W) -> yT[(b*4+g)][pix][ci] (channel-last per
// 16-channel group). One pixel-column x 16 ch = one 64 B cache line.
// -------------------------------------------------------------------------
__global__ __launch_bounds__(256) void transpose_kernel(
    const float* __restrict__ y, float* __restrict__ yT)
{
    __shared__ __align__(16) float tile[256][20];   // pad 20: aligned float4 rows
    const int t  = threadIdx.x;
    const int by = blockIdx.y;                      // (b2*4 + g) = plane-group 0..31
    const int tile_base = blockIdx.x * 256;
    #pragma unroll
    for (int ci = 0; ci < 16; ++ci)
        tile[t][ci] = y[(long)(by * 16 + ci) * HWsz + tile_base + t];
    __syncthreads();
    float* dst = yT + ((long)by * HWsz + tile_base) * 16;
    #pragma unroll
    for (int pass = 0; pass < 4; ++pass) {
        const int j = pass * 1024 + t * 4;          // 0..4095
        const int px = j >> 4, ci = j & 15;
        *reinterpret_cast<float4*>(dst + j) =
            *reinterpret_cast<const float4*>(&tile[px][ci]);
    }
}

// -------------------------------------------------------------------------
// Kernel 1: offset + mask fields. 2 pixels per thread (h and h+64) so the
// per-pixel weight-read instruction count halves. Weights staged in LDS
// (padded to float4 stride -> broadcast ds_read_b128, conflict-free) so we
// never depend on the compiler scalarizing uniform global loads.
// -------------------------------------------------------------------------
__global__ __launch_bounds__(256) void field_kernel(
    const float* __restrict__ x,
    const float* __restrict__ Weff_off, const float* __restrict__ Wraw_off,
    const float* __restrict__ off_b,
    const float* __restrict__ Weff_mask, const float* __restrict__ Wraw_mask,
    const float* __restrict__ mask_b,
    float* __restrict__ offs, float* __restrict__ maskf)
{
    __shared__ __align__(16) float wlds[3840];          // 15.4 KB
    const int tid  = threadIdx.x;
    const int p    = blockIdx.x * 256 + tid;            // pixel 0..8191 (top half)
    const int bx   = blockIdx.y;                        // x batch 0..3
    const int pass = blockIdx.z;                        // 0..3 = offs g, 4 = mask
    const int h = p >> 7, w = p & 127;                  // h in 0..63; pixel2 = h+64
    const float* xb = x + (long)bx * 64 * HWsz;

    if (pass < 4) {
        const int g = pass;
        // stage Weff_off[g] -> [ci][t][20], Wraw_off[g] -> [c][20] at 2880
        for (int i = tid; i < 2880; i += 256) {
            const int o = i % 20;
            float v = 0.f;
            if (o < 18) {
                const int t = (i / 20) % 9, ci = i / 180;
                v = Weff_off[((g * 16 + ci) * 9 + t) * 18 + o];
            }
            wlds[i] = v;
        }
        for (int i = tid; i < 960; i += 256) {
            const int o = i % 20, c = i / 20;
            wlds[2880 + i] = (o < 18) ? Wraw_off[(g * 48 + c) * 18 + o] : 0.f;
        }
        __syncthreads();

        float acc0[20], acc1[20];
        #pragma unroll
        for (int o = 0; o < 20; ++o) {
            const float b = (o < 18) ? off_b[g * 18 + o] : 0.f;
            acc0[o] = b; acc1[o] = b;
        }
        for (int ci = 0; ci < 16; ++ci) {
            const float* xp = xb + ci * HWsz;
            #pragma unroll
            for (int t = 0; t < 9; ++t) {
                const int hh0 = h + t / 3 - 1, w2 = w + t % 3 - 1;
                const int hh1 = hh0 + 64;
                float xv0 = 0.f, xv1 = 0.f;
                if ((unsigned)w2 < 128u) {
                    if ((unsigned)hh0 < 128u) xv0 = xp[hh0 * 128 + w2];
                    if ((unsigned)hh1 < 128u) xv1 = xp[hh1 * 128 + w2];
                }
                const float4* wq = reinterpret_cast<const float4*>(&wlds[(ci * 9 + t) * 20]);
                #pragma unroll
                for (int q = 0; q < 5; ++q) {
                    const float4 wv = wq[q];
                    acc0[q*4+0] = fmaf(xv0, wv.x, acc0[q*4+0]);
                    acc0[q*4+1] = fmaf(xv0, wv.y, acc0[q*4+1]);
                    acc0[q*4+2] = fmaf(xv0, wv.z, acc0[q*4+2]);
                    acc0[q*4+3] = fmaf(xv0, wv.w, acc0[q*4+3]);
                    acc1[q*4+0] = fmaf(xv1, wv.x, acc1[q*4+0]);
                    acc1[q*4+1] = fmaf(xv1, wv.y, acc1[q*4+1]);
                    acc1[q*4+2] = fmaf(xv1, wv.z, acc1[q*4+2]);
                    acc1[q*4+3] = fmaf(xv1, wv.w, acc1[q*4+3]);
                }
            }
        }
        for (int c = 0; c < 48; ++c) {
            const float xv0 = xb[(16 + c) * HWsz + p];
            const float xv1 = xb[(16 + c) * HWsz + p + 8192];
            const float4* wq = reinterpret_cast<const float4*>(&wlds[2880 + c * 20]);
            #pragma unroll
            for (int q = 0; q < 5; ++q) {
                const float4 wv = wq[q];
                acc0[q*4+0] = fmaf(xv0, wv.x, acc0[q*4+0]);
                acc0[q*4+1] = fmaf(xv0, wv.y, acc0[q*4+1]);
                acc0[q*4+2] = fmaf(xv0, wv.z, acc0[q*4+2]);
                acc0[q*4+3] = fmaf(xv0, wv.w, acc0[q*4+3]);
                acc1[q*4+0] = fmaf(xv1, wv.x, acc1[q*4+0]);
                acc1[q*4+1] = fmaf(xv1, wv.y, acc1[q*4+1]);
                acc1[q*4+2] = fmaf(xv1, wv.z, acc1[q*4+2]);
                acc1[q*4+3] = fmaf(xv1, wv.w, acc1[q*4+3]);
            }
        }
        float* op = offs + ((long)(bx * 4 + g) * 18) * HWsz + p;
        #pragma unroll
        for (int o = 0; o < 18; ++o) {
            op[(long)o * HWsz]        = acc0[o];
            op[(long)o * HWsz + 8192] = acc1[o];
        }
    } else {
        // stage Weff_mask -> [ci][t][12], Wraw_mask -> [c][12] at 1728
        for (int i = tid; i < 1728; i += 256) {
            const int o = i % 12;
            float v = 0.f;
            if (o < 9) {
                const int t = (i / 12) % 9, ci = i / 108;
                v = Weff_mask[(ci * 9 + t) * 9 + o];
            }
            wlds[i] = v;
        }
        for (int i = tid; i < 576; i += 256) {
            const int o = i % 12, c = i / 12;
            wlds[1728 + i] = (o < 9) ? Wraw_mask[c * 9 + o] : 0.f;
        }
        __syncthreads();

        float acc0[12], acc1[12];
        #pragma unroll
        for (int o = 0; o < 12; ++o) {
            const float b = (o < 9) ? mask_b[o] : 0.f;
            acc0[o] = b; acc1[o] = b;
        }
        for (int ci = 0; ci < 16; ++ci) {
            const float* xp = xb + ci * HWsz;
            #pragma unroll
            for (int t = 0; t < 9; ++t) {
                const int hh0 = h + t / 3 - 1, w2 = w + t % 3 - 1;
                const int hh1 = hh0 + 64;
                float xv0 = 0.f, xv1 = 0.f;
                if ((unsigned)w2 < 128u) {
                    if ((unsigned)hh0 < 128u) xv0 = xp[hh0 * 128 + w2];
                    if ((unsigned)hh1 < 128u) xv1 = xp[hh1 * 128 + w2];
                }
                const float4* wq = reinterpret_cast<const float4*>(&wlds[(ci * 9 + t) * 12]);
                #pragma unroll
                for (int q = 0; q < 3; ++q) {
                    const float4 wv = wq[q];
                    acc0[q*4+0] = fmaf(xv0, wv.x, acc0[q*4+0]);
                    acc0[q*4+1] = fmaf(xv0, wv.y, acc0[q*4+1]);
                    acc0[q*4+2] = fmaf(xv0, wv.z, acc0[q*4+2]);
                    acc0[q*4+3] = fmaf(xv0, wv.w, acc0[q*4+3]);
                    acc1[q*4+0] = fmaf(xv1, wv.x, acc1[q*4+0]);
                    acc1[q*4+1] = fmaf(xv1, wv.y, acc1[q*4+1]);
                    acc1[q*4+2] = fmaf(xv1, wv.z, acc1[q*4+2]);
                    acc1[q*4+3] = fmaf(xv1, wv.w, acc1[q*4+3]);
                }
            }
        }
        for (int c = 0; c < 48; ++c) {
            const float xv0 = xb[(16 + c) * HWsz + p];
            const float xv1 = xb[(16 + c) * HWsz + p + 8192];
            const float4* wq = reinterpret_cast<const float4*>(&wlds[1728 + c * 12]);
            #pragma unroll
            for (int q = 0; q < 3; ++q) {
                const float4 wv = wq[q];
                acc0[q*4+0] = fmaf(xv0, wv.x, acc0[q*4+0]);
                acc0[q*4+1] = fmaf(xv0, wv.y, acc0[q*4+1]);
                acc0[q*4+2] = fmaf(xv0, wv.z, acc0[q*4+2]);
                acc0[q*4+3] = fmaf(xv0, wv.w, acc0[q*4+3]);
                acc1[q*4+0] = fmaf(xv1, wv.x, acc1[q*4+0]);
                acc1[q*4+1] = fmaf(xv1, wv.y, acc1[q*4+1]);
                acc1[q*4+2] = fmaf(xv1, wv.z, acc1[q*4+2]);
                acc1[q*4+3] = fmaf(xv1, wv.w, acc1[q*4+3]);
            }
        }
        float* op = maskf + (long)bx * 9 * HWsz + p;
        #pragma unroll
        for (int o = 0; o < 9; ++o) {
            op[(long)o * HWsz]        = 1.0f / (1.0f + __expf(-acc0[o]));
            op[(long)o * HWsz + 8192] = 1.0f / (1.0f + __expf(-acc1[o]));
        }
    }
}

// -------------------------------------------------------------------------
// Kernel 2: modulated deformable bilinear sampling on channel-last yT.
// Lane mapping = (pixel, channel-quad): 256 threads = 64 px x 4 quads. One
// load instruction covers 16 pixels x one 64 B column-line (4 quads split
// the line) -> ~16 distinct lines/instr instead of ~64, 8 loads/lane
// instead of 16. Column clamping folded into remapped pair weights; row
// clamping into row weights; all loads unconditional and in-bounds.
// -------------------------------------------------------------------------
__global__ __launch_bounds__(256) void sample_kernel(
    const float* __restrict__ yT,
    const float* __restrict__ offs,
    const float* __restrict__ maskf,
    float* __restrict__ out)
{
    const int tid  = threadIdx.x;
    const int quad = tid & 3;                       // channel quad 0..3
    const int p    = blockIdx.x * 64 + (tid >> 2);  // pixel
    const int bg = blockIdx.y;                      // 0..15
    const int bx = bg >> 2, g = bg & 3;
    const int k  = blockIdx.z;                      // tap 0..8
    const int h = p >> 7, w = p & 127;
    const int dil = 2 * g + 1;

    const long obase = ((long)(bx * 4 + g) * 18) * HWsz + p;
    const float dy = offs[obase + (long)(2 * k) * HWsz];
    const float dx = offs[obase + (long)(2 * k + 1) * HWsz];
    const float m  = maskf[((long)bx * 9 + k) * HWsz + p];

    const float py = (float)(h + (k / 3 - 1) * dil) + dy;
    const float px = (float)(w + (k % 3 - 1) * dil) + dx;
    const float y0f = floorf(py), x0f = floorf(px);
    const float wy = py - y0f, wx = px - x0f;
    const int y0 = (int)y0f, x0 = (int)x0f;

    const bool vy0 = (unsigned)y0 < 128u, vy1 = (unsigned)(y0 + 1) < 128u;
    const int  yc0 = min(max(y0, 0), 127), yc1 = min(max(y0 + 1, 0), 127);
    const float r0 = vy0 ? (1.f - wy) * m : 0.f;
    const float r1 = vy1 ? wy * m : 0.f;

    const int  c0 = min(max(x0, 0), 126);
    const bool interior = (x0 >= 0) & (x0 <= 126);
    float b0, b1;
    if (interior)        { b0 = 1.f - wx; b1 = wx; }
    else if (x0 == -1)   { b0 = wx;       b1 = 0.f; }
    else if (x0 == 127)  { b0 = 0.f;      b1 = 1.f - wx; }
    else                 { b0 = 0.f;      b1 = 0.f; }
    const float w00 = r0 * b0, w01 = r0 * b1;
    const float w10 = r1 * b0, w11 = r1 * b1;

    const long off0 = ((long)yc0 * 128 + c0) * 16 + quad * 4;  // floats; 16B aligned
    const long off1 = ((long)yc1 * 128 + c0) * 16 + quad * 4;

    #pragma unroll
    for (int half = 0; half < 2; ++half) {
        const float* base = yT + (long)((bx + half * 4) * 4 + g) * (HWsz * 16L);
        const float4 r0a = *reinterpret_cast<const float4*>(base + off0);
        const float4 r0b = *reinterpret_cast<const float4*>(base + off0 + 16);
        const float4 r1a = *reinterpret_cast<const float4*>(base + off1);
        const float4 r1b = *reinterpret_cast<const float4*>(base + off1 + 16);
        float* op = out + ((long)((bx + half * 4) * 64 + g * 16 + quad * 4) * 9 + k) * HWsz + p;
        op[0]            = fmaf(r0a.x, w00, fmaf(r0b.x, w01, fmaf(r1a.x, w10, r1b.x * w11)));
        op[9L * HWsz]    = fmaf(r0a.y, w00, fmaf(r0b.y, w01, fmaf(r1a.y, w10, r1b.y * w11)));
        op[18L * HWsz]   = fmaf(r0a.z, w00, fmaf(r0b.z, w01, fmaf(r1a.z, w10, r1b.z * w11)));
        op[27L * HWsz]   = fmaf(r0a.w, w00, fmaf(r0b.w, w01, fmaf(r1a.w, w10, r1b.w * w11)));
    }
}

extern "C" void kernel_launch(void* const* d_in, const int* in_sizes, int n_in,
                              void* d_out, int out_size, void* d_ws, size_t ws_size,
                              hipStream_t stream) {
    const float* x       = (const float*)d_in[0];
    const float* y       = (const float*)d_in[1];
    const float* off_pw  = (const float*)d_in[2];
    const float* off_w   = (const float*)d_in[3];
    const float* off_b   = (const float*)d_in[4];
    const float* mask_pw = (const float*)d_in[5];
    const float* mask_w  = (const float*)d_in[6];
    const float* mask_b  = (const float*)d_in[7];
    float* out = (float*)d_out;

    float* ws        = (float*)d_ws;
    float* offs      = ws + OFFS_OFF;
    float* maskf     = ws + MASK_OFF;
    float* Weff_off  = ws + WEO_OFF;
    float* Wraw_off  = ws + WRO_OFF;
    float* Weff_mask = ws + WEM_OFF;
    float* Wraw_mask = ws + WRM_OFF;
    float* yT        = ws + YT_OFF;

    // 0) collapse weights (15552 work items)
    prep_kernel<<<61, 256, 0, stream>>>(off_pw, off_w, mask_pw, mask_w,
                                        Weff_off, Wraw_off, Weff_mask, Wraw_mask);
    // 0b) transpose y to channel-last groups: 64 pixel-tiles x 32 plane-groups
    transpose_kernel<<<dim3(64, 32), 256, 0, stream>>>(y, yT);
    // 1) offset + mask fields: 32 pixel-tiles (2 px/thread) x 4 batches x 5 passes
    field_kernel<<<dim3(32, 4, 5), 256, 0, stream>>>(
        x, Weff_off, Wraw_off, off_b, Weff_mask, Wraw_mask, mask_b, offs, maskf);
    // 2) deformable sampling: 256 px-tiles (64 px x 4 quads) x 16 (bx,g) x 9 taps
    sample_kernel<<<dim3(256, 16, 9), 256, 0, stream>>>(yT, offs, maskf, out);
}

// Round 5
// 545.232 us; speedup vs baseline: 1.0439x; 1.0439x over previous
//
#include <hip/hip_runtime.h>
#include <hip/hip_bf16.h>
#include <math.h>

// Problem constants (fixed by the reference's setup_inputs):
//   x: (4, 64, 128, 128)  y: (8, 64, 128, 128)
//   G=4 groups, cg=dc=16, K=3 (K2=9), dilation per group = 2g+1
//   out: (8, 64, 9, 128, 128) fp32
constexpr int HH   = 128;
constexpr int WW   = 128;
constexpr int HWsz = HH * WW;          // 16384

// ---- workspace layout (in floats) ----  (~55 MB total)
// Weight arrays are PADDED to float4-friendly strides (20 / 12) so the field
// kernel can read them as dwordx4.
constexpr long OFFS_OFF = 0;                             // offsets [4][4][18][HW]
constexpr long MASK_OFF = OFFS_OFF + 4L * 4 * 18 * HWsz; // mask   [4][9][HW]
constexpr long WEO_OFF  = MASK_OFF + 4L * 9 * HWsz;      // Weff_off  [4][16][9][20]
constexpr long WRO_OFF  = WEO_OFF + 4L * 16 * 9 * 20;    // Wraw_off  [4][48][20]
constexpr long WEM_OFF  = WRO_OFF + 4L * 48 * 20;        // Weff_mask [16][9][12]
constexpr long WRM_OFF  = WEM_OFF + 16L * 9 * 12;        // Wraw_mask [48][12]
constexpr long YT_OFF   = WRM_OFF + 48L * 12;            // yT [8*4][HW][16] ch-last
// All bases are 16B-aligned (checked: each offset*4 % 16 == 0).

// -------------------------------------------------------------------------
// Kernel 0: collapse (3x3 conv 16->16) ∘ (1x1 over first-16 channels) into a
// single effective 3x3 conv 16->O (padded stride 20/12 for dwordx4 reads),
// and transpose the raw-channel 1x1 weights.
// -------------------------------------------------------------------------
__global__ __launch_bounds__(256) void prep_kernel(
    const float* __restrict__ off_pw,   // (4,16,16,3,3)
    const float* __restrict__ off_w,    // (4,18,64)
    const float* __restrict__ mask_pw,  // (16,16,3,3)
    const float* __restrict__ mask_w,   // (9,64)
    float* __restrict__ Weff_off, float* __restrict__ Wraw_off,
    float* __restrict__ Weff_mask, float* __restrict__ Wraw_mask)
{
    const int i = blockIdx.x * 256 + threadIdx.x;
    if (i < 11520) {                       // Weff_off[g][ci][t][20]
        const int o = i % 20; int r = i / 20;
        const int t = r % 9;  r /= 9;
        const int ci = r % 16; const int g = r / 16;
        float s = 0.f;
        if (o < 18)
            for (int co = 0; co < 16; ++co)
                s += off_w[(g * 18 + o) * 64 + co] *
                     off_pw[((g * 16 + co) * 16 + ci) * 9 + t];
        Weff_off[i] = s;
    } else if (i < 11520 + 3840) {         // Wraw_off[g][c][20]
        const int j = i - 11520;
        const int o = j % 20; int r = j / 20;
        const int c = r % 48; const int g = r / 48;
        Wraw_off[j] = (o < 18) ? off_w[(g * 18 + o) * 64 + 16 + c] : 0.f;
    } else if (i < 11520 + 3840 + 1728) {  // Weff_mask[ci][t][12]
        const int j = i - 15360;
        const int o = j % 12; int r = j / 12;
        const int t = r % 9; const int ci = r / 9;
        float s = 0.f;
        if (o < 9)
            for (int co = 0; co < 16; ++co)
                s += mask_w[o * 64 + co] * mask_pw[((co * 16) + ci) * 9 + t];
        Weff_mask[j] = s;
    } else if (i < 11520 + 3840 + 1728 + 576) { // Wraw_mask[c][12]
        const int j = i - 17088;
        const int o = j % 12; const int c = j / 12;
        Wraw_mask[j] = (o < 9) ? mask_w[o * 64 + 16 + c] : 0.f;
    }
}

// -------------------------------------------------------------------------
// Kernel 0b: transpose y (B,C,H,W) -> yT[(b*4+g)][pix][ci] (channel-last per
// 16-channel group). One pixel-column x 16 ch = one 64 B cache line.
// -------------------------------------------------------------------------
__global__ __launch_bounds__(256) void transpose_kernel(
    const float* __restrict__ y, float* __restrict__ yT)
{
    __shared__ __align__(16) float tile[256][20];   // pad 20: aligned float4 rows
    const int t  = threadIdx.x;
    const int by = blockIdx.y;                      // (b2*4 + g) = plane-group 0..31
    const int tile_base = blockIdx.x * 256;
    #pragma unroll
    for (int ci = 0; ci < 16; ++ci)
        tile[t][ci] = y[(long)(by * 16 + ci) * HWsz + tile_base + t];
    __syncthreads();
    float* dst = yT + ((long)by * HWsz + tile_base) * 16;
    #pragma unroll
    for (int pass = 0; pass < 4; ++pass) {
        const int j = pass * 1024 + t * 4;          // 0..4095
        const int px = j >> 4, ci = j & 15;
        *reinterpret_cast<float4*>(dst + j) =
            *reinterpret_cast<const float4*>(&tile[px][ci]);
    }
}

// -------------------------------------------------------------------------
// Kernel 1: offset + mask fields. R1 structure (1 px/thread, wave-uniform
// GLOBAL weight reads -> scalar-cache/L1), upgraded to dwordx4 weight loads
// via the padded stride-20/12 layouts. No LDS (ds_read_b128 throughput
// ~12cyc made the R2 LDS version SLOWER than cached uniform VMEM).
// -------------------------------------------------------------------------
__global__ __launch_bounds__(256) void field_kernel(
    const float* __restrict__ x,
    const float* __restrict__ Weff_off, const float* __restrict__ Wraw_off,
    const float* __restrict__ off_b,
    const float* __restrict__ Weff_mask, const float* __restrict__ Wraw_mask,
    const float* __restrict__ mask_b,
    float* __restrict__ offs, float* __restrict__ maskf)
{
    const int p    = blockIdx.x * 256 + threadIdx.x;   // pixel 0..16383
    const int bx   = blockIdx.y;                        // x batch 0..3
    const int pass = blockIdx.z;                        // 0..3 = offs g, 4 = mask
    const int h = p >> 7, w = p & 127;
    const float* xb = x + (long)bx * 64 * HWsz;

    if (pass < 4) {
        const int g = pass;
        float acc[20];
        #pragma unroll
        for (int o = 0; o < 20; ++o) acc[o] = (o < 18) ? off_b[g * 18 + o] : 0.f;
        for (int ci = 0; ci < 16; ++ci) {
            const float* xp = xb + ci * HWsz;
            #pragma unroll
            for (int t = 0; t < 9; ++t) {
                const int hh = h + t / 3 - 1, w2 = w + t % 3 - 1;
                float xv = 0.f;
                if ((unsigned)hh < 128u && (unsigned)w2 < 128u)
                    xv = xp[hh * 128 + w2];
                const float4* wq = reinterpret_cast<const float4*>(
                    Weff_off + ((g * 16 + ci) * 9 + t) * 20);
                #pragma unroll
                for (int q = 0; q < 5; ++q) {
                    const float4 wv = wq[q];
                    acc[q*4+0] = fmaf(xv, wv.x, acc[q*4+0]);
                    acc[q*4+1] = fmaf(xv, wv.y, acc[q*4+1]);
                    acc[q*4+2] = fmaf(xv, wv.z, acc[q*4+2]);
                    acc[q*4+3] = fmaf(xv, wv.w, acc[q*4+3]);
                }
            }
        }
        for (int c = 0; c < 48; ++c) {
            const float xv = xb[(16 + c) * HWsz + p];
            const float4* wq = reinterpret_cast<const float4*>(
                Wraw_off + (g * 48 + c) * 20);
            #pragma unroll
            for (int q = 0; q < 5; ++q) {
                const float4 wv = wq[q];
                acc[q*4+0] = fmaf(xv, wv.x, acc[q*4+0]);
                acc[q*4+1] = fmaf(xv, wv.y, acc[q*4+1]);
                acc[q*4+2] = fmaf(xv, wv.z, acc[q*4+2]);
                acc[q*4+3] = fmaf(xv, wv.w, acc[q*4+3]);
            }
        }
        float* op = offs + ((long)(bx * 4 + g) * 18) * HWsz + p;
        #pragma unroll
        for (int o = 0; o < 18; ++o) op[(long)o * HWsz] = acc[o];
    } else {
        float acc[12];
        #pragma unroll
        for (int o = 0; o < 12; ++o) acc[o] = (o < 9) ? mask_b[o] : 0.f;
        for (int ci = 0; ci < 16; ++ci) {
            const float* xp = xb + ci * HWsz;
            #pragma unroll
            for (int t = 0; t < 9; ++t) {
                const int hh = h + t / 3 - 1, w2 = w + t % 3 - 1;
                float xv = 0.f;
                if ((unsigned)hh < 128u && (unsigned)w2 < 128u)
                    xv = xp[hh * 128 + w2];
                const float4* wq = reinterpret_cast<const float4*>(
                    Weff_mask + (ci * 9 + t) * 12);
                #pragma unroll
                for (int q = 0; q < 3; ++q) {
                    const float4 wv = wq[q];
                    acc[q*4+0] = fmaf(xv, wv.x, acc[q*4+0]);
                    acc[q*4+1] = fmaf(xv, wv.y, acc[q*4+1]);
                    acc[q*4+2] = fmaf(xv, wv.z, acc[q*4+2]);
                    acc[q*4+3] = fmaf(xv, wv.w, acc[q*4+3]);
                }
            }
        }
        for (int c = 0; c < 48; ++c) {
            const float xv = xb[(16 + c) * HWsz + p];
            const float4* wq = reinterpret_cast<const float4*>(Wraw_mask + c * 12);
            #pragma unroll
            for (int q = 0; q < 3; ++q) {
                const float4 wv = wq[q];
                acc[q*4+0] = fmaf(xv, wv.x, acc[q*4+0]);
                acc[q*4+1] = fmaf(xv, wv.y, acc[q*4+1]);
                acc[q*4+2] = fmaf(xv, wv.z, acc[q*4+2]);
                acc[q*4+3] = fmaf(xv, wv.w, acc[q*4+3]);
            }
        }
        float* op = maskf + (long)bx * 9 * HWsz + p;
        #pragma unroll
        for (int o = 0; o < 9; ++o)
            op[(long)o * HWsz] = 1.0f / (1.0f + __expf(-acc[o]));
    }
}

// -------------------------------------------------------------------------
// Kernel 2: modulated deformable bilinear sampling on channel-last yT.
// Quad lane-map (unchanged from R2): 256 threads = 64 px x 4 quads; each
// gather instruction's 4 quad-lanes merge into one 64 B line -> ~16 distinct
// lines/instr. 1 dwordx4 request per output float. Column clamping folded
// into remapped pair weights; row clamping into row weights.
// -------------------------------------------------------------------------
__global__ __launch_bounds__(256) void sample_kernel(
    const float* __restrict__ yT,
    const float* __restrict__ offs,
    const float* __restrict__ maskf,
    float* __restrict__ out)
{
    const int tid  = threadIdx.x;
    const int quad = tid & 3;                       // channel quad 0..3
    const int p    = blockIdx.x * 64 + (tid >> 2);  // pixel
    const int bg = blockIdx.y;                      // 0..15
    const int bx = bg >> 2, g = bg & 3;
    const int k  = blockIdx.z;                      // tap 0..8
    const int h = p >> 7, w = p & 127;
    const int dil = 2 * g + 1;

    const long obase = ((long)(bx * 4 + g) * 18) * HWsz + p;
    const float dy = offs[obase + (long)(2 * k) * HWsz];
    const float dx = offs[obase + (long)(2 * k + 1) * HWsz];
    const float m  = maskf[((long)bx * 9 + k) * HWsz + p];

    const float py = (float)(h + (k / 3 - 1) * dil) + dy;
    const float px = (float)(w + (k % 3 - 1) * dil) + dx;
    const float y0f = floorf(py), x0f = floorf(px);
    const float wy = py - y0f, wx = px - x0f;
    const int y0 = (int)y0f, x0 = (int)x0f;

    const bool vy0 = (unsigned)y0 < 128u, vy1 = (unsigned)(y0 + 1) < 128u;
    const int  yc0 = min(max(y0, 0), 127), yc1 = min(max(y0 + 1, 0), 127);
    const float r0 = vy0 ? (1.f - wy) * m : 0.f;
    const float r1 = vy1 ? wy * m : 0.f;

    const int  c0 = min(max(x0, 0), 126);
    const bool interior = (x0 >= 0) & (x0 <= 126);
    float b0, b1;
    if (interior)        { b0 = 1.f - wx; b1 = wx; }
    else if (x0 == -1)   { b0 = wx;       b1 = 0.f; }
    else if (x0 == 127)  { b0 = 0.f;      b1 = 1.f - wx; }
    else                 { b0 = 0.f;      b1 = 0.f; }
    const float w00 = r0 * b0, w01 = r0 * b1;
    const float w10 = r1 * b0, w11 = r1 * b1;

    const long off0 = ((long)yc0 * 128 + c0) * 16 + quad * 4;  // floats; 16B aligned
    const long off1 = ((long)yc1 * 128 + c0) * 16 + quad * 4;

    #pragma unroll
    for (int half = 0; half < 2; ++half) {
        const float* base = yT + (long)((bx + half * 4) * 4 + g) * (HWsz * 16L);
        const float4 r0a = *reinterpret_cast<const float4*>(base + off0);
        const float4 r0b = *reinterpret_cast<const float4*>(base + off0 + 16);
        const float4 r1a = *reinterpret_cast<const float4*>(base + off1);
        const float4 r1b = *reinterpret_cast<const float4*>(base + off1 + 16);
        float* op = out + ((long)((bx + half * 4) * 64 + g * 16 + quad * 4) * 9 + k) * HWsz + p;
        op[0]            = fmaf(r0a.x, w00, fmaf(r0b.x, w01, fmaf(r1a.x, w10, r1b.x * w11)));
        op[9L * HWsz]    = fmaf(r0a.y, w00, fmaf(r0b.y, w01, fmaf(r1a.y, w10, r1b.y * w11)));
        op[18L * HWsz]   = fmaf(r0a.z, w00, fmaf(r0b.z, w01, fmaf(r1a.z, w10, r1b.z * w11)));
        op[27L * HWsz]   = fmaf(r0a.w, w00, fmaf(r0b.w, w01, fmaf(r1a.w, w10, r1b.w * w11)));
    }
}

extern "C" void kernel_launch(void* const* d_in, const int* in_sizes, int n_in,
                              void* d_out, int out_size, void* d_ws, size_t ws_size,
                              hipStream_t stream) {
    const float* x       = (const float*)d_in[0];
    const float* y       = (const float*)d_in[1];
    const float* off_pw  = (const float*)d_in[2];
    const float* off_w   = (const float*)d_in[3];
    const float* off_b   = (const float*)d_in[4];
    const float* mask_pw = (const float*)d_in[5];
    const float* mask_w  = (const float*)d_in[6];
    const float* mask_b  = (const float*)d_in[7];
    float* out = (float*)d_out;

    float* ws        = (float*)d_ws;
    float* offs      = ws + OFFS_OFF;
    float* maskf     = ws + MASK_OFF;
    float* Weff_off  = ws + WEO_OFF;
    float* Wraw_off  = ws + WRO_OFF;
    float* Weff_mask = ws + WEM_OFF;
    float* Wraw_mask = ws + WRM_OFF;
    float* yT        = ws + YT_OFF;

    // 0) collapse weights (17664 padded work items)
    prep_kernel<<<69, 256, 0, stream>>>(off_pw, off_w, mask_pw, mask_w,
                                        Weff_off, Wraw_off, Weff_mask, Wraw_mask);
    // 0b) transpose y to channel-last groups: 64 pixel-tiles x 32 plane-groups
    transpose_kernel<<<dim3(64, 32), 256, 0, stream>>>(y, yT);
    // 1) offset + mask fields: 64 pixel-tiles x 4 batches x 5 passes
    field_kernel<<<dim3(64, 4, 5), 256, 0, stream>>>(
        x, Weff_off, Wraw_off, off_b, Weff_mask, Wraw_mask, mask_b, offs, maskf);
    // 2) deformable sampling: 256 px-tiles (64 px x 4 quads) x 16 (bx,g) x 9 taps
    sample_kernel<<<dim3(256, 16, 9), 256, 0, stream>>>(yT, offs, maskf, out);
}

// Round 6
// 533.218 us; speedup vs baseline: 1.0674x; 1.0225x over previous
//
#include <hip/hip_runtime.h>
#include <hip/hip_bf16.h>
#include <math.h>

// Problem constants (fixed by the reference's setup_inputs):
//   x: (4, 64, 128, 128)  y: (8, 64, 128, 128)
//   G=4 groups, cg=dc=16, K=3 (K2=9), dilation per group = 2g+1
//   out: (8, 64, 9, 128, 128) fp32
constexpr int HH   = 128;
constexpr int WW   = 128;
constexpr int HWsz = HH * WW;          // 16384

// ---- workspace layout (in floats) ----  (~55 MB total)
// Weight arrays are PADDED to float4-friendly strides (20 / 12) so the field
// kernel can read them as dwordx4 (wave-uniform -> scalar cache).
constexpr long OFFS_OFF = 0;                             // offsets [4][4][18][HW]
constexpr long MASK_OFF = OFFS_OFF + 4L * 4 * 18 * HWsz; // mask   [4][9][HW]
constexpr long WEO_OFF  = MASK_OFF + 4L * 9 * HWsz;      // Weff_off  [4][16][9][20]
constexpr long WRO_OFF  = WEO_OFF + 4L * 16 * 9 * 20;    // Wraw_off  [4][48][20]
constexpr long WEM_OFF  = WRO_OFF + 4L * 48 * 20;        // Weff_mask [16][9][12]
constexpr long WRM_OFF  = WEM_OFF + 16L * 9 * 12;        // Wraw_mask [48][12]
constexpr long YT_OFF   = WRM_OFF + 48L * 12;            // yT [8*4][HW][16] ch-last
// All bases are 16B-aligned (checked: each offset*4 % 16 == 0).

// -------------------------------------------------------------------------
// Kernel 0: collapse (3x3 conv 16->16) ∘ (1x1 over first-16 channels) into a
// single effective 3x3 conv 16->O (padded stride 20/12 for dwordx4 reads),
// and transpose the raw-channel 1x1 weights.
// -------------------------------------------------------------------------
__global__ __launch_bounds__(256) void prep_kernel(
    const float* __restrict__ off_pw,   // (4,16,16,3,3)
    const float* __restrict__ off_w,    // (4,18,64)
    const float* __restrict__ mask_pw,  // (16,16,3,3)
    const float* __restrict__ mask_w,   // (9,64)
    float* __restrict__ Weff_off, float* __restrict__ Wraw_off,
    float* __restrict__ Weff_mask, float* __restrict__ Wraw_mask)
{
    const int i = blockIdx.x * 256 + threadIdx.x;
    if (i < 11520) {                       // Weff_off[g][ci][t][20]
        const int o = i % 20; int r = i / 20;
        const int t = r % 9;  r /= 9;
        const int ci = r % 16; const int g = r / 16;
        float s = 0.f;
        if (o < 18)
            for (int co = 0; co < 16; ++co)
                s += off_w[(g * 18 + o) * 64 + co] *
                     off_pw[((g * 16 + co) * 16 + ci) * 9 + t];
        Weff_off[i] = s;
    } else if (i < 11520 + 3840) {         // Wraw_off[g][c][20]
        const int j = i - 11520;
        const int o = j % 20; int r = j / 20;
        const int c = r % 48; const int g = r / 48;
        Wraw_off[j] = (o < 18) ? off_w[(g * 18 + o) * 64 + 16 + c] : 0.f;
    } else if (i < 11520 + 3840 + 1728) {  // Weff_mask[ci][t][12]
        const int j = i - 15360;
        const int o = j % 12; int r = j / 12;
        const int t = r % 9; const int ci = r / 9;
        float s = 0.f;
        if (o < 9)
            for (int co = 0; co < 16; ++co)
                s += mask_w[o * 64 + co] * mask_pw[((co * 16) + ci) * 9 + t];
        Weff_mask[j] = s;
    } else if (i < 11520 + 3840 + 1728 + 576) { // Wraw_mask[c][12]
        const int j = i - 17088;
        const int o = j % 12; const int c = j / 12;
        Wraw_mask[j] = (o < 9) ? mask_w[o * 64 + 16 + c] : 0.f;
    }
}

// -------------------------------------------------------------------------
// Kernel 0b: transpose y (B,C,H,W) -> yT[(b*4+g)][pix][ci] (channel-last per
// 16-channel group). One pixel-column x 16 ch = one 64 B cache line.
// -------------------------------------------------------------------------
__global__ __launch_bounds__(256) void transpose_kernel(
    const float* __restrict__ y, float* __restrict__ yT)
{
    __shared__ __align__(16) float tile[256][20];   // pad 20: aligned float4 rows
    const int t  = threadIdx.x;
    const int by = blockIdx.y;                      // (b2*4 + g) = plane-group 0..31
    const int tile_base = blockIdx.x * 256;
    #pragma unroll
    for (int ci = 0; ci < 16; ++ci)
        tile[t][ci] = y[(long)(by * 16 + ci) * HWsz + tile_base + t];
    __syncthreads();
    float* dst = yT + ((long)by * HWsz + tile_base) * 16;
    #pragma unroll
    for (int pass = 0; pass < 4; ++pass) {
        const int j = pass * 1024 + t * 4;          // 0..4095
        const int px = j >> 4, ci = j & 15;
        *reinterpret_cast<float4*>(dst + j) =
            *reinterpret_cast<const float4*>(&tile[px][ci]);
    }
}

// -------------------------------------------------------------------------
// Kernel 1: offset + mask fields (unchanged from R5: 1 px/thread, uniform
// global float4 weight loads -> scalar cache).
// -------------------------------------------------------------------------
__global__ __launch_bounds__(256) void field_kernel(
    const float* __restrict__ x,
    const float* __restrict__ Weff_off, const float* __restrict__ Wraw_off,
    const float* __restrict__ off_b,
    const float* __restrict__ Weff_mask, const float* __restrict__ Wraw_mask,
    const float* __restrict__ mask_b,
    float* __restrict__ offs, float* __restrict__ maskf)
{
    const int p    = blockIdx.x * 256 + threadIdx.x;   // pixel 0..16383
    const int bx   = blockIdx.y;                        // x batch 0..3
    const int pass = blockIdx.z;                        // 0..3 = offs g, 4 = mask
    const int h = p >> 7, w = p & 127;
    const float* xb = x + (long)bx * 64 * HWsz;

    if (pass < 4) {
        const int g = pass;
        float acc[20];
        #pragma unroll
        for (int o = 0; o < 20; ++o) acc[o] = (o < 18) ? off_b[g * 18 + o] : 0.f;
        for (int ci = 0; ci < 16; ++ci) {
            const float* xp = xb + ci * HWsz;
            #pragma unroll
            for (int t = 0; t < 9; ++t) {
                const int hh = h + t / 3 - 1, w2 = w + t % 3 - 1;
                float xv = 0.f;
                if ((unsigned)hh < 128u && (unsigned)w2 < 128u)
                    xv = xp[hh * 128 + w2];
                const float4* wq = reinterpret_cast<const float4*>(
                    Weff_off + ((g * 16 + ci) * 9 + t) * 20);
                #pragma unroll
                for (int q = 0; q < 5; ++q) {
                    const float4 wv = wq[q];
                    acc[q*4+0] = fmaf(xv, wv.x, acc[q*4+0]);
                    acc[q*4+1] = fmaf(xv, wv.y, acc[q*4+1]);
                    acc[q*4+2] = fmaf(xv, wv.z, acc[q*4+2]);
                    acc[q*4+3] = fmaf(xv, wv.w, acc[q*4+3]);
                }
            }
        }
        for (int c = 0; c < 48; ++c) {
            const float xv = xb[(16 + c) * HWsz + p];
            const float4* wq = reinterpret_cast<const float4*>(
                Wraw_off + (g * 48 + c) * 20);
            #pragma unroll
            for (int q = 0; q < 5; ++q) {
                const float4 wv = wq[q];
                acc[q*4+0] = fmaf(xv, wv.x, acc[q*4+0]);
                acc[q*4+1] = fmaf(xv, wv.y, acc[q*4+1]);
                acc[q*4+2] = fmaf(xv, wv.z, acc[q*4+2]);
                acc[q*4+3] = fmaf(xv, wv.w, acc[q*4+3]);
            }
        }
        float* op = offs + ((long)(bx * 4 + g) * 18) * HWsz + p;
        #pragma unroll
        for (int o = 0; o < 18; ++o) op[(long)o * HWsz] = acc[o];
    } else {
        float acc[12];
        #pragma unroll
        for (int o = 0; o < 12; ++o) acc[o] = (o < 9) ? mask_b[o] : 0.f;
        for (int ci = 0; ci < 16; ++ci) {
            const float* xp = xb + ci * HWsz;
            #pragma unroll
            for (int t = 0; t < 9; ++t) {
                const int hh = h + t / 3 - 1, w2 = w + t % 3 - 1;
                float xv = 0.f;
                if ((unsigned)hh < 128u && (unsigned)w2 < 128u)
                    xv = xp[hh * 128 + w2];
                const float4* wq = reinterpret_cast<const float4*>(
                    Weff_mask + (ci * 9 + t) * 12);
                #pragma unroll
                for (int q = 0; q < 3; ++q) {
                    const float4 wv = wq[q];
                    acc[q*4+0] = fmaf(xv, wv.x, acc[q*4+0]);
                    acc[q*4+1] = fmaf(xv, wv.y, acc[q*4+1]);
                    acc[q*4+2] = fmaf(xv, wv.z, acc[q*4+2]);
                    acc[q*4+3] = fmaf(xv, wv.w, acc[q*4+3]);
                }
            }
        }
        for (int c = 0; c < 48; ++c) {
            const float xv = xb[(16 + c) * HWsz + p];
            const float4* wq = reinterpret_cast<const float4*>(Wraw_mask + c * 12);
            #pragma unroll
            for (int q = 0; q < 3; ++q) {
                const float4 wv = wq[q];
                acc[q*4+0] = fmaf(xv, wv.x, acc[q*4+0]);
                acc[q*4+1] = fmaf(xv, wv.y, acc[q*4+1]);
                acc[q*4+2] = fmaf(xv, wv.z, acc[q*4+2]);
                acc[q*4+3] = fmaf(xv, wv.w, acc[q*4+3]);
            }
        }
        float* op = maskf + (long)bx * 9 * HWsz + p;
        #pragma unroll
        for (int o = 0; o < 9; ++o)
            op[(long)o * HWsz] = 1.0f / (1.0f + __expf(-acc[o]));
    }
}

// -------------------------------------------------------------------------
// Kernel 2: modulated deformable bilinear sampling on channel-last yT.
// R1's per-pixel lane mapping (best measured) + ALL 9 TAPS FUSED per thread:
// the 9 taps' neighborhoods overlap, so each y line is fetched from HBM ~once
// instead of 9x, and offs/mask addressing is amortized. Per tap: 32 dwordx4
// gathers (2 rows x 2 col-lines x 16ch x 2 halves), 32 coalesced stores.
// Column clamping folded into remapped pair weights; row clamping into row
// weights; all loads unconditional and in-bounds. No runtime-indexed local
// arrays (rule #20) - per-tap scalars only.
// -------------------------------------------------------------------------
__global__ __launch_bounds__(256) void sample_kernel(
    const float* __restrict__ yT,
    const float* __restrict__ offs,
    const float* __restrict__ maskf,
    float* __restrict__ out)
{
    const int p  = blockIdx.x * 256 + threadIdx.x;  // pixel 0..16383
    const int bg = blockIdx.y;                      // 0..15
    const int bx = bg >> 2, g = bg & 3;
    const int h = p >> 7, w = p & 127;
    const int dil = 2 * g + 1;

    const long obase = ((long)(bx * 4 + g) * 18) * HWsz + p;
    const float* base0 = yT + (long)((bx    ) * 4 + g) * (HWsz * 16L);
    const float* base1 = yT + (long)((bx + 4) * 4 + g) * (HWsz * 16L);
    float* out0 = out + ((long)((bx    ) * 64 + g * 16) * 9) * HWsz + p;
    float* out1 = out + ((long)((bx + 4) * 64 + g * 16) * 9) * HWsz + p;

    for (int k = 0; k < 9; ++k) {
        const float dy = offs[obase + (long)(2 * k) * HWsz];
        const float dx = offs[obase + (long)(2 * k + 1) * HWsz];
        const float m  = maskf[((long)bx * 9 + k) * HWsz + p];

        const float py = (float)(h + (k / 3 - 1) * dil) + dy;
        const float px = (float)(w + (k % 3 - 1) * dil) + dx;
        const float y0f = floorf(py), x0f = floorf(px);
        const float wy = py - y0f, wx = px - x0f;
        const int y0 = (int)y0f, x0 = (int)x0f;

        const bool vy0 = (unsigned)y0 < 128u, vy1 = (unsigned)(y0 + 1) < 128u;
        const int  yc0 = min(max(y0, 0), 127), yc1 = min(max(y0 + 1, 0), 127);
        const float r0 = vy0 ? (1.f - wy) * m : 0.f;
        const float r1 = vy1 ? wy * m : 0.f;

        const int  c0 = min(max(x0, 0), 126);
        const bool interior = (x0 >= 0) & (x0 <= 126);
        float b0, b1;
        if (interior)        { b0 = 1.f - wx; b1 = wx; }
        else if (x0 == -1)   { b0 = wx;       b1 = 0.f; }
        else if (x0 == 127)  { b0 = 0.f;      b1 = 1.f - wx; }
        else                 { b0 = 0.f;      b1 = 0.f; }
        const float w00 = r0 * b0, w01 = r0 * b1;
        const float w10 = r1 * b0, w11 = r1 * b1;

        const long off0 = ((long)yc0 * 128 + c0) * 16;   // floats; 64B aligned
        const long off1 = ((long)yc1 * 128 + c0) * 16;

        #pragma unroll
        for (int half = 0; half < 2; ++half) {
            const float* base = half ? base1 : base0;
            const float4* A0 = reinterpret_cast<const float4*>(base + off0);
            const float4* A1 = reinterpret_cast<const float4*>(base + off1);

            float acc[16];
            float4 q[8];
            #pragma unroll
            for (int j = 0; j < 8; ++j) q[j] = A0[j];    // row0: cols c0|c0+1 x 16ch
            #pragma unroll
            for (int ci = 0; ci < 16; ++ci) {
                const float vA = reinterpret_cast<const float*>(q)[ci];
                const float vB = reinterpret_cast<const float*>(q)[16 + ci];
                acc[ci] = fmaf(vA, w00, vB * w01);
            }
            #pragma unroll
            for (int j = 0; j < 8; ++j) q[j] = A1[j];    // row1
            float* op = (half ? out1 : out0) + (long)k * HWsz;
            #pragma unroll
            for (int ci = 0; ci < 16; ++ci) {
                const float vA = reinterpret_cast<const float*>(q)[ci];
                const float vB = reinterpret_cast<const float*>(q)[16 + ci];
                op[(long)ci * 9 * HWsz] = fmaf(vA, w10, fmaf(vB, w11, acc[ci]));
            }
        }
    }
}

extern "C" void kernel_launch(void* const* d_in, const int* in_sizes, int n_in,
                              void* d_out, int out_size, void* d_ws, size_t ws_size,
                              hipStream_t stream) {
    const float* x       = (const float*)d_in[0];
    const float* y       = (const float*)d_in[1];
    const float* off_pw  = (const float*)d_in[2];
    const float* off_w   = (const float*)d_in[3];
    const float* off_b   = (const float*)d_in[4];
    const float* mask_pw = (const float*)d_in[5];
    const float* mask_w  = (const float*)d_in[6];
    const float* mask_b  = (const float*)d_in[7];
    float* out = (float*)d_out;

    float* ws        = (float*)d_ws;
    float* offs      = ws + OFFS_OFF;
    float* maskf     = ws + MASK_OFF;
    float* Weff_off  = ws + WEO_OFF;
    float* Wraw_off  = ws + WRO_OFF;
    float* Weff_mask = ws + WEM_OFF;
    float* Wraw_mask = ws + WRM_OFF;
    float* yT        = ws + YT_OFF;

    // 0) collapse weights (17664 padded work items)
    prep_kernel<<<69, 256, 0, stream>>>(off_pw, off_w, mask_pw, mask_w,
                                        Weff_off, Wraw_off, Weff_mask, Wraw_mask);
    // 0b) transpose y to channel-last groups: 64 pixel-tiles x 32 plane-groups
    transpose_kernel<<<dim3(64, 32), 256, 0, stream>>>(y, yT);
    // 1) offset + mask fields: 64 pixel-tiles x 4 batches x 5 passes
    field_kernel<<<dim3(64, 4, 5), 256, 0, stream>>>(
        x, Weff_off, Wraw_off, off_b, Weff_mask, Wraw_mask, mask_b, offs, maskf);
    // 2) deformable sampling, all taps fused: 64 pixel-tiles x 16 (bx,g)
    sample_kernel<<<dim3(64, 16), 256, 0, stream>>>(yT, offs, maskf, out);
}

// Round 7
// 523.324 us; speedup vs baseline: 1.0875x; 1.0189x over previous
//
#include <hip/hip_runtime.h>
#include <hip/hip_bf16.h>
#include <math.h>

// Problem constants (fixed by the reference's setup_inputs):
//   x: (4, 64, 128, 128)  y: (8, 64, 128, 128)
//   G=4 groups, cg=dc=16, K=3 (K2=9), dilation per group = 2g+1
//   out: (8, 64, 9, 128, 128) fp32
constexpr int HH   = 128;
constexpr int WW   = 128;
constexpr int HWsz = HH * WW;          // 16384

// ---- workspace layout (in floats) ----  (~55 MB total)
constexpr long OFFS_OFF = 0;                             // offsets [4][4][18][HW]
constexpr long MASK_OFF = OFFS_OFF + 4L * 4 * 18 * HWsz; // mask   [4][9][HW]
constexpr long WEO_OFF  = MASK_OFF + 4L * 9 * HWsz;      // Weff_off  [4][16][9][18]
constexpr long WRO_OFF  = WEO_OFF + 4L * 16 * 9 * 18;    // Wraw_off  [4][48][18]
constexpr long WEM_OFF  = WRO_OFF + 4L * 48 * 18;        // Weff_mask [16][9][9]
constexpr long WRM_OFF  = WEM_OFF + 16L * 9 * 9;         // Wraw_mask [48][9]
constexpr long YT_OFF   = WRM_OFF + 48L * 9;             // yT [8*4][HW][16] ch-last
// YT_OFF = 5,323,968 floats -> 16B aligned (x4 = 21,295,872, %16 == 0)

// -------------------------------------------------------------------------
// Kernel 0 (R1-exact): collapse (3x3 conv 16->16) ∘ (1x1 over first-16
// channels) into an effective 3x3 conv 16->O; transpose raw-channel weights.
// -------------------------------------------------------------------------
__global__ __launch_bounds__(256) void prep_kernel(
    const float* __restrict__ off_pw,   // (4,16,16,3,3)
    const float* __restrict__ off_w,    // (4,18,64)
    const float* __restrict__ mask_pw,  // (16,16,3,3)
    const float* __restrict__ mask_w,   // (9,64)
    float* __restrict__ Weff_off, float* __restrict__ Wraw_off,
    float* __restrict__ Weff_mask, float* __restrict__ Wraw_mask)
{
    const int i = blockIdx.x * 256 + threadIdx.x;
    if (i < 10368) {                       // Weff_off[g][ci][t][o]
        const int o = i % 18; int r = i / 18;
        const int t = r % 9;  r /= 9;
        const int ci = r % 16; const int g = r / 16;
        float s = 0.f;
        for (int co = 0; co < 16; ++co)
            s += off_w[(g * 18 + o) * 64 + co] *
                 off_pw[((g * 16 + co) * 16 + ci) * 9 + t];
        Weff_off[i] = s;
    } else if (i < 10368 + 3456) {         // Wraw_off[g][c][o]
        const int j = i - 10368;
        const int o = j % 18; int r = j / 18;
        const int c = r % 48; const int g = r / 48;
        Wraw_off[j] = off_w[(g * 18 + o) * 64 + 16 + c];
    } else if (i < 10368 + 3456 + 1296) {  // Weff_mask[ci][t][o]
        const int j = i - 13824;
        const int o = j % 9; int r = j / 9;
        const int t = r % 9; const int ci = r / 9;
        float s = 0.f;
        for (int co = 0; co < 16; ++co)
            s += mask_w[o * 64 + co] * mask_pw[((co * 16) + ci) * 9 + t];
        Weff_mask[j] = s;
    } else if (i < 10368 + 3456 + 1296 + 432) { // Wraw_mask[c][o]
        const int j = i - 15120;
        const int o = j % 9; const int c = j / 9;
        Wraw_mask[j] = mask_w[o * 64 + 16 + c];
    }
}

// -------------------------------------------------------------------------
// Kernel 0b: transpose y (B,C,H,W) -> yT[(b*4+g)][pix][ci] (channel-last per
// 16-channel group). One pixel-column x 16 ch = one 64 B cache line.
// -------------------------------------------------------------------------
__global__ __launch_bounds__(256) void transpose_kernel(
    const float* __restrict__ y, float* __restrict__ yT)
{
    __shared__ __align__(16) float tile[256][20];   // pad 20: aligned float4 rows
    const int t  = threadIdx.x;
    const int by = blockIdx.y;                      // (b2*4 + g) = plane-group 0..31
    const int tile_base = blockIdx.x * 256;
    #pragma unroll
    for (int ci = 0; ci < 16; ++ci)
        tile[t][ci] = y[(long)(by * 16 + ci) * HWsz + tile_base + t];
    __syncthreads();
    float* dst = yT + ((long)by * HWsz + tile_base) * 16;
    #pragma unroll
    for (int pass = 0; pass < 4; ++pass) {
        const int j = pass * 1024 + t * 4;          // 0..4095
        const int px = j >> 4, ci = j & 15;
        *reinterpret_cast<float4*>(dst + j) =
            *reinterpret_cast<const float4*>(&tile[px][ci]);
    }
}

// -------------------------------------------------------------------------
// Kernel 1 (R1-exact): offset + mask fields. 1 px/thread; weight indices are
// wave-uniform scalar loads (compiler scalarizes to s_load -> free alongside
// VALU). The float4-weight variant (R5/R6) emitted per-lane vector broadcasts
// and cost ~+22 us -- do NOT "vectorize" these.
// -------------------------------------------------------------------------
__global__ __launch_bounds__(256) void field_kernel(
    const float* __restrict__ x,
    const float* __restrict__ Weff_off, const float* __restrict__ Wraw_off,
    const float* __restrict__ off_b,
    const float* __restrict__ Weff_mask, const float* __restrict__ Wraw_mask,
    const float* __restrict__ mask_b,
    float* __restrict__ offs, float* __restrict__ maskf)
{
    const int p    = blockIdx.x * 256 + threadIdx.x;   // pixel 0..16383
    const int bx   = blockIdx.y;                        // x batch 0..3
    const int pass = blockIdx.z;                        // 0..3 = offs g, 4 = mask
    const int h = p >> 7, w = p & 127;
    const float* xb = x + (long)bx * 64 * HWsz;

    if (pass < 4) {
        const int g = pass;
        float acc[18];
        #pragma unroll
        for (int o = 0; o < 18; ++o) acc[o] = off_b[g * 18 + o];
        for (int ci = 0; ci < 16; ++ci) {
            const float* xp = xb + ci * HWsz;
            #pragma unroll
            for (int t = 0; t < 9; ++t) {
                const int hh = h + t / 3 - 1, w2 = w + t % 3 - 1;
                float xv = 0.f;
                if ((unsigned)hh < 128u && (unsigned)w2 < 128u)
                    xv = xp[hh * 128 + w2];
                const float* wp = Weff_off + ((g * 16 + ci) * 9 + t) * 18;
                #pragma unroll
                for (int o = 0; o < 18; ++o) acc[o] = fmaf(xv, wp[o], acc[o]);
            }
        }
        for (int c = 0; c < 48; ++c) {
            const float xv = xb[(16 + c) * HWsz + p];
            const float* wp = Wraw_off + (g * 48 + c) * 18;
            #pragma unroll
            for (int o = 0; o < 18; ++o) acc[o] = fmaf(xv, wp[o], acc[o]);
        }
        float* op = offs + ((long)(bx * 4 + g) * 18) * HWsz + p;
        #pragma unroll
        for (int o = 0; o < 18; ++o) op[(long)o * HWsz] = acc[o];
    } else {
        float acc[9];
        #pragma unroll
        for (int o = 0; o < 9; ++o) acc[o] = mask_b[o];
        for (int ci = 0; ci < 16; ++ci) {
            const float* xp = xb + ci * HWsz;
            #pragma unroll
            for (int t = 0; t < 9; ++t) {
                const int hh = h + t / 3 - 1, w2 = w + t % 3 - 1;
                float xv = 0.f;
                if ((unsigned)hh < 128u && (unsigned)w2 < 128u)
                    xv = xp[hh * 128 + w2];
                const float* wp = Weff_mask + (ci * 9 + t) * 9;
                #pragma unroll
                for (int o = 0; o < 9; ++o) acc[o] = fmaf(xv, wp[o], acc[o]);
            }
        }
        for (int c = 0; c < 48; ++c) {
            const float xv = xb[(16 + c) * HWsz + p];
            const float* wp = Wraw_mask + c * 9;
            #pragma unroll
            for (int o = 0; o < 9; ++o) acc[o] = fmaf(xv, wp[o], acc[o]);
        }
        float* op = maskf + (long)bx * 9 * HWsz + p;
        #pragma unroll
        for (int o = 0; o < 9; ++o)
            op[(long)o * HWsz] = 1.0f / (1.0f + __expf(-acc[o]));
    }
}

// -------------------------------------------------------------------------
// Kernel 2 (R6-exact): modulated deformable bilinear sampling on channel-last
// yT. Per-pixel lane mapping, all 9 taps fused per thread (y-line reuse
// across taps; offs/mask addressing amortized). Per tap: 32 dwordx4 gathers
// + 32 coalesced stores. Column clamping folded into remapped pair weights;
// row clamping into row weights; all loads unconditional and in-bounds.
// -------------------------------------------------------------------------
__global__ __launch_bounds__(256) void sample_kernel(
    const float* __restrict__ yT,
    const float* __restrict__ offs,
    const float* __restrict__ maskf,
    float* __restrict__ out)
{
    const int p  = blockIdx.x * 256 + threadIdx.x;  // pixel 0..16383
    const int bg = blockIdx.y;                      // 0..15
    const int bx = bg >> 2, g = bg & 3;
    const int h = p >> 7, w = p & 127;
    const int dil = 2 * g + 1;

    const long obase = ((long)(bx * 4 + g) * 18) * HWsz + p;
    const float* base0 = yT + (long)((bx    ) * 4 + g) * (HWsz * 16L);
    const float* base1 = yT + (long)((bx + 4) * 4 + g) * (HWsz * 16L);
    float* out0 = out + ((long)((bx    ) * 64 + g * 16) * 9) * HWsz + p;
    float* out1 = out + ((long)((bx + 4) * 64 + g * 16) * 9) * HWsz + p;

    for (int k = 0; k < 9; ++k) {
        const float dy = offs[obase + (long)(2 * k) * HWsz];
        const float dx = offs[obase + (long)(2 * k + 1) * HWsz];
        const float m  = maskf[((long)bx * 9 + k) * HWsz + p];

        const float py = (float)(h + (k / 3 - 1) * dil) + dy;
        const float px = (float)(w + (k % 3 - 1) * dil) + dx;
        const float y0f = floorf(py), x0f = floorf(px);
        const float wy = py - y0f, wx = px - x0f;
        const int y0 = (int)y0f, x0 = (int)x0f;

        const bool vy0 = (unsigned)y0 < 128u, vy1 = (unsigned)(y0 + 1) < 128u;
        const int  yc0 = min(max(y0, 0), 127), yc1 = min(max(y0 + 1, 0), 127);
        const float r0 = vy0 ? (1.f - wy) * m : 0.f;
        const float r1 = vy1 ? wy * m : 0.f;

        const int  c0 = min(max(x0, 0), 126);
        const bool interior = (x0 >= 0) & (x0 <= 126);
        float b0, b1;
        if (interior)        { b0 = 1.f - wx; b1 = wx; }
        else if (x0 == -1)   { b0 = wx;       b1 = 0.f; }
        else if (x0 == 127)  { b0 = 0.f;      b1 = 1.f - wx; }
        else                 { b0 = 0.f;      b1 = 0.f; }
        const float w00 = r0 * b0, w01 = r0 * b1;
        const float w10 = r1 * b0, w11 = r1 * b1;

        const long off0 = ((long)yc0 * 128 + c0) * 16;   // floats; 64B aligned
        const long off1 = ((long)yc1 * 128 + c0) * 16;

        #pragma unroll
        for (int half = 0; half < 2; ++half) {
            const float* base = half ? base1 : base0;
            const float4* A0 = reinterpret_cast<const float4*>(base + off0);
            const float4* A1 = reinterpret_cast<const float4*>(base + off1);

            float acc[16];
            float4 q[8];
            #pragma unroll
            for (int j = 0; j < 8; ++j) q[j] = A0[j];    // row0: cols c0|c0+1 x 16ch
            #pragma unroll
            for (int ci = 0; ci < 16; ++ci) {
                const float vA = reinterpret_cast<const float*>(q)[ci];
                const float vB = reinterpret_cast<const float*>(q)[16 + ci];
                acc[ci] = fmaf(vA, w00, vB * w01);
            }
            #pragma unroll
            for (int j = 0; j < 8; ++j) q[j] = A1[j];    // row1
            float* op = (half ? out1 : out0) + (long)k * HWsz;
            #pragma unroll
            for (int ci = 0; ci < 16; ++ci) {
                const float vA = reinterpret_cast<const float*>(q)[ci];
                const float vB = reinterpret_cast<const float*>(q)[16 + ci];
                op[(long)ci * 9 * HWsz] = fmaf(vA, w10, fmaf(vB, w11, acc[ci]));
            }
        }
    }
}

extern "C" void kernel_launch(void* const* d_in, const int* in_sizes, int n_in,
                              void* d_out, int out_size, void* d_ws, size_t ws_size,
                              hipStream_t stream) {
    const float* x       = (const float*)d_in[0];
    const float* y       = (const float*)d_in[1];
    const float* off_pw  = (const float*)d_in[2];
    const float* off_w   = (const float*)d_in[3];
    const float* off_b   = (const float*)d_in[4];
    const float* mask_pw = (const float*)d_in[5];
    const float* mask_w  = (const float*)d_in[6];
    const float* mask_b  = (const float*)d_in[7];
    float* out = (float*)d_out;

    float* ws        = (float*)d_ws;
    float* offs      = ws + OFFS_OFF;
    float* maskf     = ws + MASK_OFF;
    float* Weff_off  = ws + WEO_OFF;
    float* Wraw_off  = ws + WRO_OFF;
    float* Weff_mask = ws + WEM_OFF;
    float* Wraw_mask = ws + WRM_OFF;
    float* yT        = ws + YT_OFF;

    // 0) collapse weights (15552 work items)
    prep_kernel<<<61, 256, 0, stream>>>(off_pw, off_w, mask_pw, mask_w,
                                        Weff_off, Wraw_off, Weff_mask, Wraw_mask);
    // 0b) transpose y to channel-last groups: 64 pixel-tiles x 32 plane-groups
    transpose_kernel<<<dim3(64, 32), 256, 0, stream>>>(y, yT);
    // 1) offset + mask fields: 64 pixel-tiles x 4 batches x 5 passes
    field_kernel<<<dim3(64, 4, 5), 256, 0, stream>>>(
        x, Weff_off, Wraw_off, off_b, Weff_mask, Wraw_mask, mask_b, offs, maskf);
    // 2) deformable sampling, all taps fused: 64 pixel-tiles x 16 (bx,g)
    sample_kernel<<<dim3(64, 16), 256, 0, stream>>>(yT, offs, maskf, out);
}